// Round 12
// baseline (762.198 us; speedup 1.0000x reference)
//
#include <hip/hip_runtime.h>

#define N_TRAIN 100000
#define DIM 768
#define NQ 1024
#define BN 96                  // cols per chunk (fp8); LDS ~78KB -> 2 WGs/CU
#define NCHUNK 1042            // ceil(100000/96), tail chunk has 64 valid
#define MARGIN 36.0f           // d2 margin for fp8 filter (>=2x worst-case err)
#define MAXC 65536

typedef float f32x4 __attribute__((ext_vector_type(4)));
typedef unsigned int u32x4 __attribute__((ext_vector_type(4)));
typedef unsigned int u32x3 __attribute__((ext_vector_type(3)));
typedef unsigned long long u64;

// ---- fp32 -> OCP e4m3 pack / unpack: HW cvt when available ----
__device__ __forceinline__ unsigned char f2q_soft(float f) {
  unsigned int u = __builtin_bit_cast(unsigned int, f);
  unsigned int s = (u >> 24) & 0x80u;
  int e = (int)((u >> 23) & 0xFFu) - 127;
  unsigned int m = u & 0x7FFFFFu;
  if (e < -9) return (unsigned char)s;
  if (e < -6) {
    int rb = 20 + (-6 - e);
    unsigned int full = 0x800000u | m;
    unsigned int q = full >> rb;
    unsigned int rem = full & ((1u << rb) - 1u);
    unsigned int half = 1u << (rb - 1);
    q += (rem > half) || (rem == half && (q & 1u));
    return (unsigned char)(s | q);
  }
  unsigned int q = m >> 20;
  unsigned int rem = m & 0xFFFFFu;
  q += (rem > 0x80000u) || (rem == 0x80000u && (q & 1u));
  int ee = e + 7;
  if (q == 8u) { q = 0u; ee += 1; }
  if (ee >= 16) return (unsigned char)(s | 0x7Eu);
  return (unsigned char)(s | ((unsigned)ee << 3) | q);
}
__device__ __forceinline__ float q2f_soft(unsigned char h) {
  unsigned int s = ((unsigned int)h & 0x80u) << 24;
  int ee = (h >> 3) & 15; unsigned int m = h & 7u;
  if (ee == 0) {
    float v = (float)m * 0.001953125f;
    return __builtin_bit_cast(float, s | __builtin_bit_cast(unsigned int, v));
  }
  return __builtin_bit_cast(float, s | ((unsigned int)(ee + 120) << 23) | (m << 20));
}
__device__ __forceinline__ unsigned int pk_lo(float a, float b) {
#if __has_builtin(__builtin_amdgcn_cvt_pk_fp8_f32)
  return (unsigned int)__builtin_amdgcn_cvt_pk_fp8_f32(a, b, 0, false);
#else
  return (unsigned)f2q_soft(a) | ((unsigned)f2q_soft(b) << 8);
#endif
}
__device__ __forceinline__ unsigned int pk_hi(unsigned int old, float a, float b) {
#if __has_builtin(__builtin_amdgcn_cvt_pk_fp8_f32)
  return (unsigned int)__builtin_amdgcn_cvt_pk_fp8_f32(a, b, (int)old, true);
#else
  return (old & 0xFFFFu) | (((unsigned)f2q_soft(a) | ((unsigned)f2q_soft(b) << 8)) << 16);
#endif
}
#if __has_builtin(__builtin_amdgcn_cvt_f32_fp8)
#define UNPK(v, sel) __builtin_amdgcn_cvt_f32_fp8((int)(v), (sel))
#else
#define UNPK(v, sel) q2f_soft((unsigned char)((v) >> (8 * (sel))))
#endif
// unpack all 4 lanes of a packed u32 with LITERAL sels (builtin requires it)
#define UNPK4(dst, v) do { \
    (dst)[0] = UNPK((v), 0); (dst)[1] = UNPK((v), 1); \
    (dst)[2] = UNPK((v), 2); (dst)[3] = UNPK((v), 3); } while (0)

// monotonic float<->uint for atomicMin
__device__ __forceinline__ unsigned int fenc(float f) {
  unsigned int u = __builtin_bit_cast(unsigned int, f);
  return (u & 0x80000000u) ? ~u : (u | 0x80000000u);
}
__device__ __forceinline__ float fdec(unsigned int u) {
  u = (u & 0x80000000u) ? (u & 0x7FFFFFFFu) : ~u;
  return __builtin_bit_cast(float, u);
}

// ---------------- init ----------------
__global__ void initK(unsigned long long* res, unsigned int* gmin, unsigned int* cnt) {
  int t = threadIdx.x;
  res[t] = ~0ull;
  gmin[t] = 0xFFFFFFFFu;
  if (t < 2) cnt[t] = 0u;
}

// ------- queries -> fp8, pre-swizzled MFMA A-fragment layout -------
__global__ void convA(const float* __restrict__ x, unsigned char* __restrict__ Asw) {
  int t = blockIdx.x * 256 + threadIdx.x;   // 0..98303
  int l = t & 63;
  int fragid = t >> 6;                      // 0..1535 (64 mf x 24 ks)
  int mf = fragid / 24;
  int ks = fragid - mf * 24;
  int row = mf * 16 + (l & 15);
  int k = ks * 32 + (l >> 4) * 8;
  const float* src = x + (size_t)row * DIM + k;
  f32x4 v0 = *(const f32x4*)(src);
  f32x4 v1 = *(const f32x4*)(src + 4);
  unsigned int lo = pk_lo(v0[0], v0[1]); lo = pk_hi(lo, v0[2], v0[3]);
  unsigned int hi = pk_lo(v1[0], v1[1]); hi = pk_hi(hi, v1[2], v1[3]);
  *(u64*)(Asw + (size_t)fragid * 512 + l * 8) = (u64)lo | ((u64)hi << 32);
}

// ---------------- Pass A: fp8 filter GEMM + 96-col block-min ----------------
// Also writes the quantized tile to global X8 (fp8 shadow of X_train, 77MB,
// L3-resident) + per-row quantized norms T2 for passC1's column-level filter.
// WRITE_SIZE baseline is now ~81MB (bmin 4.3 + X8 77); spill alarm = >>90MB.
__global__ __launch_bounds__(512, 4) void passA(
    const float* __restrict__ Xt, const unsigned char* __restrict__ Asw,
    float* __restrict__ bmin, unsigned int* __restrict__ X8,
    float* __restrict__ T2, int writeX8) {
  __shared__ __align__(16) unsigned char Bs[BN * DIM];  // 73728 B
  __shared__ float t2p[BN][16];
  __shared__ float t2s[BN];
  const int tid = threadIdx.x;
  const int chunk = blockIdx.x;

  // ---- stage: 96 rows -> fp8 LDS (swizzled) + quantized sum-of-squares ----
#pragma unroll
  for (int i = 0; i < 3; ++i) {
    int idx = tid + i * 512;                 // 0..1535 = 96 rows x 16 slices
    int c = idx >> 4, sl = idx & 15;
    int n = chunk * BN + c;
    int base = c * DIM + sl * 48;
    int xmS = (c & 15) << 4;
    float ss = 0.f;
    if (n < N_TRAIN) {
      const float* src = Xt + (size_t)n * DIM + sl * 48;
#pragma unroll
      for (int j = 0; j < 3; ++j) {
        f32x4 v0 = *(const f32x4*)(src + j * 16);
        f32x4 v1 = *(const f32x4*)(src + j * 16 + 4);
        f32x4 v2 = *(const f32x4*)(src + j * 16 + 8);
        f32x4 v3 = *(const f32x4*)(src + j * 16 + 12);
        u32x4 w;
        w[0] = pk_lo(v0[0], v0[1]); w[0] = pk_hi(w[0], v0[2], v0[3]);
        w[1] = pk_lo(v1[0], v1[1]); w[1] = pk_hi(w[1], v1[2], v1[3]);
        w[2] = pk_lo(v2[0], v2[1]); w[2] = pk_hi(w[2], v2[2], v2[3]);
        w[3] = pk_lo(v3[0], v3[1]); w[3] = pk_hi(w[3], v3[2], v3[3]);
#pragma unroll
        for (int u = 0; u < 4; ++u) {
          float dq[4];
          UNPK4(dq, w[u]);
          ss = fmaf(dq[0], dq[0], ss); ss = fmaf(dq[1], dq[1], ss);
          ss = fmaf(dq[2], dq[2], ss); ss = fmaf(dq[3], dq[3], ss);
        }
        *(u32x4*)(&Bs[(base + j * 16) ^ xmS]) = w;
        if (writeX8) *(u32x4*)(X8 + (size_t)n * 192 + sl * 12 + j * 4) = w;
      }
    } else {
      u32x4 w; w[0] = 0; w[1] = 0; w[2] = 0; w[3] = 0;
#pragma unroll
      for (int j = 0; j < 3; ++j) *(u32x4*)(&Bs[(base + j * 16) ^ xmS]) = w;
    }
    t2p[c][sl] = ss;
  }
  __syncthreads();
  if (tid < BN) {
    float s = 0.f;
#pragma unroll
    for (int j = 0; j < 16; ++j) s += t2p[tid][j];
    int n = chunk * BN + tid;
    t2s[tid] = (n < N_TRAIN) ? s : 3.0e38f;
    if (writeX8 && n < N_TRAIN) T2[n] = s;
  }
  __syncthreads();

  const int wid = tid >> 6;
  const int l = tid & 63;
  const int lc = l & 15;
  const int lg = l >> 4;

  int cb[6], xm[6];                          // un-swizzled bases + XOR masks
#pragma unroll
  for (int cf = 0; cf < 6; ++cf) {
    int c = cf * 16 + lc;
    cb[cf] = c * DIM + lg * 8;
    xm[cf] = (c & 15) << 4;
  }

  for (int mt = 0; mt < 4; ++mt) {           // 4 m-tiles of 256 query rows
    f32x4 acc[2][6];
#pragma unroll
    for (int rf = 0; rf < 2; ++rf)
#pragma unroll
      for (int cf = 0; cf < 6; ++cf) {
        acc[rf][cf][0] = 0.f; acc[rf][cf][1] = 0.f;
        acc[rf][cf][2] = 0.f; acc[rf][cf][3] = 0.f;
      }
    const int mfbase = mt * 16 + wid * 2;    // wave owns 32 rows = 2 row-frags
    const unsigned char* ap = Asw + (size_t)mfbase * 24 * 512 + l * 8;

    long a0 = *(const long*)(ap);
    long a1 = *(const long*)(ap + 24 * 512);
    long b[6], a0n, a1n, bn[6];
#pragma unroll
    for (int cf = 0; cf < 6; ++cf)
      b[cf] = *(const long*)(&Bs[cb[cf] ^ xm[cf]]);

#pragma unroll 1
    for (int ks = 0; ks < 24; ks += 2) {     // even/odd 1-deep pipeline
      int k1 = ks + 1;
      a0n = *(const long*)(ap + k1 * 512);
      a1n = *(const long*)(ap + (24 + k1) * 512);
#pragma unroll
      for (int cf = 0; cf < 6; ++cf)
        bn[cf] = *(const long*)(&Bs[(cb[cf] + k1 * 32) ^ xm[cf]]);
#pragma unroll
      for (int cf = 0; cf < 6; ++cf) {
        acc[0][cf] = __builtin_amdgcn_mfma_f32_16x16x32_fp8_fp8(a0, b[cf], acc[0][cf], 0, 0, 0);
        acc[1][cf] = __builtin_amdgcn_mfma_f32_16x16x32_fp8_fp8(a1, b[cf], acc[1][cf], 0, 0, 0);
      }
      int k2 = (ks + 2 < 24) ? ks + 2 : 0;
      a0 = *(const long*)(ap + k2 * 512);
      a1 = *(const long*)(ap + (24 + k2) * 512);
#pragma unroll
      for (int cf = 0; cf < 6; ++cf)
        b[cf] = *(const long*)(&Bs[(cb[cf] + k2 * 32) ^ xm[cf]]);
#pragma unroll
      for (int cf = 0; cf < 6; ++cf) {
        acc[0][cf] = __builtin_amdgcn_mfma_f32_16x16x32_fp8_fp8(a0n, bn[cf], acc[0][cf], 0, 0, 0);
        acc[1][cf] = __builtin_amdgcn_mfma_f32_16x16x32_fp8_fp8(a1n, bn[cf], acc[1][cf], 0, 0, 0);
      }
    }

    // ---- epilogue: min over 96 cols ----
    const int rowbase = mt * 256 + wid * 32;
#pragma unroll
    for (int rf = 0; rf < 2; ++rf) {
#pragma unroll
      for (int reg = 0; reg < 4; ++reg) {
        float v = t2s[lc] - 2.f * acc[rf][0][reg];
#pragma unroll
        for (int cf = 1; cf < 6; ++cf)
          v = fminf(v, t2s[cf * 16 + lc] - 2.f * acc[rf][cf][reg]);
#pragma unroll
        for (int s = 1; s < 16; s <<= 1) v = fminf(v, __shfl_xor(v, s));
        if (lc == 0)
          bmin[(size_t)chunk * NQ + rowbase + rf * 16 + lg * 4 + reg] = v;
      }
    }
  }
}

// ------- Pass B1: per-query global min -------
__global__ __launch_bounds__(256) void passB1(const float* __restrict__ bmin,
                                              unsigned int* __restrict__ gmin) {
  int qg = blockIdx.x >> 4, cs = blockIdx.x & 15;
  int w = threadIdx.x >> 6, l = threadIdx.x & 63;
  int q = qg * 64 + l;
  float m = 3.0e38f;
  for (int j = cs * 4 + w; j < NCHUNK; j += 64)
    m = fminf(m, bmin[(size_t)j * NQ + q]);
  __shared__ float sm[4][64];
  sm[w][l] = m;
  __syncthreads();
  if (threadIdx.x < 64) {
    float v = fminf(fminf(sm[0][l], sm[1][l]), fminf(sm[2][l], sm[3][l]));
    atomicMin(&gmin[q], fenc(v));
  }
}

// ------- Pass B2: emit candidate blocks within min+MARGIN -------
__global__ __launch_bounds__(256) void passB2(const float* __restrict__ bmin,
                                              const unsigned int* __restrict__ gmin,
                                              unsigned int* __restrict__ cnt,
                                              unsigned int* __restrict__ cand) {
  int qg = blockIdx.x >> 4, cs = blockIdx.x & 15;
  int w = threadIdx.x >> 6, l = threadIdx.x & 63;
  int q = qg * 64 + l;
  float thr = fdec(gmin[q]) + MARGIN;
  for (int j = cs * 4 + w; j < NCHUNK; j += 64) {
    if (bmin[(size_t)j * NQ + q] <= thr) {
      unsigned int pos = atomicAdd(cnt, 1u);
      if (pos < MAXC) cand[pos] = ((unsigned int)q << 16) | (unsigned int)j;
    }
  }
}

// ---- Pass C1: fp8 column-level filter over X8 (L3-resident) ----
__global__ __launch_bounds__(256) void passC1(
    const float* __restrict__ x, const unsigned int* __restrict__ X8,
    const float* __restrict__ T2, const unsigned int* __restrict__ gmin,
    const unsigned int* __restrict__ cnt, const unsigned int* __restrict__ cand,
    unsigned int* __restrict__ cnt2, unsigned int* __restrict__ cand2) {
  unsigned int count = *cnt;
  if (count > MAXC) count = MAXC;
  int w = threadIdx.x >> 6, l = threadIdx.x & 63;
  for (unsigned int t = blockIdx.x * 4 + w; t < count; t += gridDim.x * 4) {
    unsigned int cd = cand[t];
    int q = cd >> 16;
    int blk = cd & 0xFFFF;
    float thr = fdec(gmin[q]) + MARGIN;
    // quantize this lane's 12 query dims (same pk path as stage => identical)
    float xv[12];
    {
      const float* xq = x + (size_t)q * DIM + l * 12;
      f32x4 a = *(const f32x4*)(xq);
      f32x4 b = *(const f32x4*)(xq + 4);
      f32x4 c = *(const f32x4*)(xq + 8);
      unsigned int w0 = pk_lo(a[0], a[1]); w0 = pk_hi(w0, a[2], a[3]);
      unsigned int w1 = pk_lo(b[0], b[1]); w1 = pk_hi(w1, b[2], b[3]);
      unsigned int w2 = pk_lo(c[0], c[1]); w2 = pk_hi(w2, c[2], c[3]);
      UNPK4(&xv[0], w0); UNPK4(&xv[4], w1); UNPK4(&xv[8], w2);
    }
    int n0 = blk * BN;
    int ncap = (n0 + BN <= N_TRAIN) ? BN : (N_TRAIN - n0);
    for (int col = 0; col < ncap; ++col) {
      int n = n0 + col;
      u32x3 tw = *(const u32x3*)(X8 + (size_t)n * 192 + l * 3);
      float tv[12];
      UNPK4(&tv[0], tw[0]); UNPK4(&tv[4], tw[1]); UNPK4(&tv[8], tw[2]);
      float s = 0.f;
#pragma unroll
      for (int i = 0; i < 12; ++i) s = fmaf(tv[i], xv[i], s);
#pragma unroll
      for (int sh = 1; sh < 64; sh <<= 1) s += __shfl_xor(s, sh);
      if (l == 0) {
        float val = T2[n] - 2.f * s;
        if (val <= thr) {
          unsigned int pos = atomicAdd(cnt2, 1u);
          if (pos < MAXC) cand2[pos] = ((unsigned int)q << 17) | (unsigned int)n;
        }
      }
    }
  }
}

// ---- Pass C2: exact fp32 on surviving columns (~10MB of reads) ----
__global__ __launch_bounds__(256) void passC2(
    const float* __restrict__ x, const float* __restrict__ Xt,
    const unsigned int* __restrict__ cnt2, const unsigned int* __restrict__ cand2,
    unsigned long long* __restrict__ res) {
  unsigned int count = *cnt2;
  if (count > MAXC) count = MAXC;
  int w = threadIdx.x >> 6, l = threadIdx.x & 63;
  for (unsigned int t = blockIdx.x * 4 + w; t < count; t += gridDim.x * 4) {
    unsigned int cd = cand2[t];
    int q = cd >> 17;
    int n = cd & 0x1FFFF;
    const float* xq = x + (size_t)q * DIM;
    const float* tn = Xt + (size_t)n * DIM;
    float s = 0.f;
#pragma unroll
    for (int i = 0; i < 12; ++i) {
      float d = xq[i * 64 + l] - tn[i * 64 + l];
      s = fmaf(d, d, s);
    }
#pragma unroll
    for (int sh = 1; sh < 64; sh <<= 1) s += __shfl_xor(s, sh);
    if (l == 0) {
      unsigned long long key =
          ((unsigned long long)__builtin_bit_cast(unsigned int, s) << 32) | (unsigned int)n;
      atomicMin(res + q, key);                // min d2, tie -> lowest index
    }
  }
}

// ---- fallback direct exact pass (R10) if ws too small for X8 ----
__global__ __launch_bounds__(256) void passC_direct(
    const float* __restrict__ x, const float* __restrict__ Xt,
    const unsigned int* __restrict__ cnt, const unsigned int* __restrict__ cand,
    unsigned long long* __restrict__ res) {
  unsigned int count = *cnt;
  if (count > MAXC) count = MAXC;
  int w = threadIdx.x >> 6, l = threadIdx.x & 63;
  for (unsigned int t = blockIdx.x * 4 + w; t < count; t += gridDim.x * 4) {
    unsigned int cd = cand[t];
    int q = cd >> 16;
    int blk = cd & 0xFFFF;
    const float* xq = x + (size_t)q * DIM;
    float xr[12];
#pragma unroll
    for (int i = 0; i < 12; ++i) xr[i] = xq[i * 64 + l];
    unsigned long long best = ~0ull;
    int n0 = blk * BN;
    int ncap = (n0 + BN <= N_TRAIN) ? BN : (N_TRAIN - n0);
    for (int col = 0; col < ncap; ++col) {
      const float* tn = Xt + (size_t)(n0 + col) * DIM;
      float s = 0.f;
#pragma unroll
      for (int i = 0; i < 12; ++i) {
        float d = xr[i] - tn[i * 64 + l];
        s = fmaf(d, d, s);
      }
#pragma unroll
      for (int sh = 1; sh < 64; sh <<= 1) s += __shfl_xor(s, sh);
      if (l == 0) {
        unsigned long long key =
            ((unsigned long long)__builtin_bit_cast(unsigned int, s) << 32) | (unsigned int)(n0 + col);
        best = (key < best) ? key : best;
      }
    }
    if (l == 0) atomicMin(res + q, best);
  }
}

// ---------------- Pass D: gather ----------------
__global__ void passD(const unsigned long long* __restrict__ res,
                      const float* __restrict__ Y, float* __restrict__ out) {
  int t = blockIdx.x * 256 + threadIdx.x;
  if (t < NQ * 24) {
    int q = t / 24, j = t - q * 24;
    unsigned int idx = (unsigned int)(res[q] & 0xFFFFFFFFu);
    out[t] = Y[(size_t)idx * 24 + j];
  }
}

extern "C" void kernel_launch(void* const* d_in, const int* in_sizes, int n_in,
                              void* d_out, int out_size, void* d_ws, size_t ws_size,
                              hipStream_t stream) {
  const float* x  = (const float*)d_in[0];   // [1024][768]
  const float* Xt = (const float*)d_in[1];   // [100000][768]
  const float* Y  = (const float*)d_in[2];   // [100000][24]
  float* out = (float*)d_out;                // [1024*24]
  char* ws = (char*)d_ws;
  unsigned long long* res  = (unsigned long long*)(ws);        // 8192 B
  unsigned int*       cnt  = (unsigned int*)(ws + 8192);       // cnt[0], cnt2=cnt[1]
  unsigned int*       gmin = (unsigned int*)(ws + 8448);       // 4096 B
  unsigned int*       cand = (unsigned int*)(ws + 12544);      // 256 KB
  unsigned int*       cand2= (unsigned int*)(ws + 274688);     // 256 KB
  unsigned char*      Asw  = (unsigned char*)(ws + 536832);    // 768 KB
  float*              T2   = (float*)(ws + 1323264);           // 400 KB
  float*              bmin = (float*)(ws + 1723392);           // 4.27 MB
  unsigned int*       X8   = (unsigned int*)(ws + 5991424);    // 76.8 MB

  int useX8 = (ws_size >= 82791424ull) ? 1 : 0;

  hipLaunchKernelGGL(initK,  dim3(1),      dim3(1024), 0, stream, res, gmin, cnt);
  hipLaunchKernelGGL(convA,  dim3(384),    dim3(256),  0, stream, x, Asw);
  hipLaunchKernelGGL(passA,  dim3(NCHUNK), dim3(512),  0, stream, Xt, Asw, bmin, X8, T2, useX8);
  hipLaunchKernelGGL(passB1, dim3(256),    dim3(256),  0, stream, bmin, gmin);
  hipLaunchKernelGGL(passB2, dim3(256),    dim3(256),  0, stream, bmin, gmin, cnt, cand);
  if (useX8) {
    hipLaunchKernelGGL(passC1, dim3(512),  dim3(256),  0, stream,
                       x, X8, T2, gmin, cnt, cand, cnt + 1, cand2);
    hipLaunchKernelGGL(passC2, dim3(256),  dim3(256),  0, stream,
                       x, Xt, cnt + 1, cand2, res);
  } else {
    hipLaunchKernelGGL(passC_direct, dim3(512), dim3(256), 0, stream,
                       x, Xt, cnt, cand, res);
  }
  hipLaunchKernelGGL(passD,  dim3(96),     dim3(256),  0, stream, res, Y, out);
}

// Round 13
// 494.465 us; speedup vs baseline: 1.5415x; 1.5415x over previous
//
#include <hip/hip_runtime.h>

#define N_TRAIN 100000
#define DIM 768
#define NQ 1024
#define BN 96                  // cols per chunk (fp8); LDS ~78KB -> 2 WGs/CU
#define NCHUNK 1042            // ceil(100000/96), tail chunk has 64 valid
#define MARGIN 36.0f           // d2 margin for fp8 filter (>=2x worst-case err)
#define MAXC 65536

typedef float f32x4 __attribute__((ext_vector_type(4)));
typedef unsigned int u32x4 __attribute__((ext_vector_type(4)));
typedef unsigned int u32x3 __attribute__((ext_vector_type(3)));
typedef unsigned long long u64;

// ---- fp32 -> OCP e4m3 pack / unpack: HW cvt when available ----
__device__ __forceinline__ unsigned char f2q_soft(float f) {
  unsigned int u = __builtin_bit_cast(unsigned int, f);
  unsigned int s = (u >> 24) & 0x80u;
  int e = (int)((u >> 23) & 0xFFu) - 127;
  unsigned int m = u & 0x7FFFFFu;
  if (e < -9) return (unsigned char)s;
  if (e < -6) {
    int rb = 20 + (-6 - e);
    unsigned int full = 0x800000u | m;
    unsigned int q = full >> rb;
    unsigned int rem = full & ((1u << rb) - 1u);
    unsigned int half = 1u << (rb - 1);
    q += (rem > half) || (rem == half && (q & 1u));
    return (unsigned char)(s | q);
  }
  unsigned int q = m >> 20;
  unsigned int rem = m & 0xFFFFFu;
  q += (rem > 0x80000u) || (rem == 0x80000u && (q & 1u));
  int ee = e + 7;
  if (q == 8u) { q = 0u; ee += 1; }
  if (ee >= 16) return (unsigned char)(s | 0x7Eu);
  return (unsigned char)(s | ((unsigned)ee << 3) | q);
}
__device__ __forceinline__ float q2f_soft(unsigned char h) {
  unsigned int s = ((unsigned int)h & 0x80u) << 24;
  int ee = (h >> 3) & 15; unsigned int m = h & 7u;
  if (ee == 0) {
    float v = (float)m * 0.001953125f;
    return __builtin_bit_cast(float, s | __builtin_bit_cast(unsigned int, v));
  }
  return __builtin_bit_cast(float, s | ((unsigned int)(ee + 120) << 23) | (m << 20));
}
__device__ __forceinline__ unsigned int pk_lo(float a, float b) {
#if __has_builtin(__builtin_amdgcn_cvt_pk_fp8_f32)
  return (unsigned int)__builtin_amdgcn_cvt_pk_fp8_f32(a, b, 0, false);
#else
  return (unsigned)f2q_soft(a) | ((unsigned)f2q_soft(b) << 8);
#endif
}
__device__ __forceinline__ unsigned int pk_hi(unsigned int old, float a, float b) {
#if __has_builtin(__builtin_amdgcn_cvt_pk_fp8_f32)
  return (unsigned int)__builtin_amdgcn_cvt_pk_fp8_f32(a, b, (int)old, true);
#else
  return (old & 0xFFFFu) | (((unsigned)f2q_soft(a) | ((unsigned)f2q_soft(b) << 8)) << 16);
#endif
}
#if __has_builtin(__builtin_amdgcn_cvt_f32_fp8)
#define UNPK(v, sel) __builtin_amdgcn_cvt_f32_fp8((int)(v), (sel))
#else
#define UNPK(v, sel) q2f_soft((unsigned char)((v) >> (8 * (sel))))
#endif
// unpack all 4 lanes of a packed u32 with LITERAL sels (builtin requires it)
#define UNPK4(dst, v) do { \
    (dst)[0] = UNPK((v), 0); (dst)[1] = UNPK((v), 1); \
    (dst)[2] = UNPK((v), 2); (dst)[3] = UNPK((v), 3); } while (0)

// monotonic float<->uint for atomicMin
__device__ __forceinline__ unsigned int fenc(float f) {
  unsigned int u = __builtin_bit_cast(unsigned int, f);
  return (u & 0x80000000u) ? ~u : (u | 0x80000000u);
}
__device__ __forceinline__ float fdec(unsigned int u) {
  u = (u & 0x80000000u) ? (u & 0x7FFFFFFFu) : ~u;
  return __builtin_bit_cast(float, u);
}

// ---------------- init ----------------
__global__ void initK(unsigned long long* res, unsigned int* gmin, unsigned int* cnt) {
  int t = threadIdx.x;
  res[t] = ~0ull;
  gmin[t] = 0xFFFFFFFFu;
  if (t < 2) cnt[t] = 0u;
}

// ------- queries -> fp8, pre-swizzled MFMA A-fragment layout -------
__global__ void convA(const float* __restrict__ x, unsigned char* __restrict__ Asw) {
  int t = blockIdx.x * 256 + threadIdx.x;   // 0..98303
  int l = t & 63;
  int fragid = t >> 6;                      // 0..1535 (64 mf x 24 ks)
  int mf = fragid / 24;
  int ks = fragid - mf * 24;
  int row = mf * 16 + (l & 15);
  int k = ks * 32 + (l >> 4) * 8;
  const float* src = x + (size_t)row * DIM + k;
  f32x4 v0 = *(const f32x4*)(src);
  f32x4 v1 = *(const f32x4*)(src + 4);
  unsigned int lo = pk_lo(v0[0], v0[1]); lo = pk_hi(lo, v0[2], v0[3]);
  unsigned int hi = pk_lo(v1[0], v1[1]); hi = pk_hi(hi, v1[2], v1[3]);
  *(u64*)(Asw + (size_t)fragid * 512 + l * 8) = (u64)lo | ((u64)hi << 32);
}

// ---------------- Pass A: fp8 filter GEMM + 96-col block-min ----------------
// Also writes the quantized tile to global X8 (fp8 shadow of X_train, 77MB)
// + per-row quantized norms T2 for passC1's column-level filter.
// WRITE_SIZE baseline ~81MB (bmin 4.3 + X8 77); spill alarm = >>90MB.
__global__ __launch_bounds__(512, 4) void passA(
    const float* __restrict__ Xt, const unsigned char* __restrict__ Asw,
    float* __restrict__ bmin, unsigned int* __restrict__ X8,
    float* __restrict__ T2, int writeX8) {
  __shared__ __align__(16) unsigned char Bs[BN * DIM];  // 73728 B
  __shared__ float t2p[BN][16];
  __shared__ float t2s[BN];
  const int tid = threadIdx.x;
  const int chunk = blockIdx.x;

  // ---- stage: 96 rows -> fp8 LDS (swizzled) + quantized sum-of-squares ----
#pragma unroll
  for (int i = 0; i < 3; ++i) {
    int idx = tid + i * 512;                 // 0..1535 = 96 rows x 16 slices
    int c = idx >> 4, sl = idx & 15;
    int n = chunk * BN + c;
    int base = c * DIM + sl * 48;
    int xmS = (c & 15) << 4;
    float ss = 0.f;
    if (n < N_TRAIN) {
      const float* src = Xt + (size_t)n * DIM + sl * 48;
#pragma unroll
      for (int j = 0; j < 3; ++j) {
        f32x4 v0 = *(const f32x4*)(src + j * 16);
        f32x4 v1 = *(const f32x4*)(src + j * 16 + 4);
        f32x4 v2 = *(const f32x4*)(src + j * 16 + 8);
        f32x4 v3 = *(const f32x4*)(src + j * 16 + 12);
        u32x4 w;
        w[0] = pk_lo(v0[0], v0[1]); w[0] = pk_hi(w[0], v0[2], v0[3]);
        w[1] = pk_lo(v1[0], v1[1]); w[1] = pk_hi(w[1], v1[2], v1[3]);
        w[2] = pk_lo(v2[0], v2[1]); w[2] = pk_hi(w[2], v2[2], v2[3]);
        w[3] = pk_lo(v3[0], v3[1]); w[3] = pk_hi(w[3], v3[2], v3[3]);
#pragma unroll
        for (int u = 0; u < 4; ++u) {
          float dq[4];
          UNPK4(dq, w[u]);
          ss = fmaf(dq[0], dq[0], ss); ss = fmaf(dq[1], dq[1], ss);
          ss = fmaf(dq[2], dq[2], ss); ss = fmaf(dq[3], dq[3], ss);
        }
        *(u32x4*)(&Bs[(base + j * 16) ^ xmS]) = w;
        if (writeX8) *(u32x4*)(X8 + (size_t)n * 192 + sl * 12 + j * 4) = w;
      }
    } else {
      u32x4 w; w[0] = 0; w[1] = 0; w[2] = 0; w[3] = 0;
#pragma unroll
      for (int j = 0; j < 3; ++j) *(u32x4*)(&Bs[(base + j * 16) ^ xmS]) = w;
    }
    t2p[c][sl] = ss;
  }
  __syncthreads();
  if (tid < BN) {
    float s = 0.f;
#pragma unroll
    for (int j = 0; j < 16; ++j) s += t2p[tid][j];
    int n = chunk * BN + tid;
    t2s[tid] = (n < N_TRAIN) ? s : 3.0e38f;
    if (writeX8 && n < N_TRAIN) T2[n] = s;
  }
  __syncthreads();

  const int wid = tid >> 6;
  const int l = tid & 63;
  const int lc = l & 15;
  const int lg = l >> 4;

  int cb[6], xm[6];                          // un-swizzled bases + XOR masks
#pragma unroll
  for (int cf = 0; cf < 6; ++cf) {
    int c = cf * 16 + lc;
    cb[cf] = c * DIM + lg * 8;
    xm[cf] = (c & 15) << 4;
  }

  for (int mt = 0; mt < 4; ++mt) {           // 4 m-tiles of 256 query rows
    f32x4 acc[2][6];
#pragma unroll
    for (int rf = 0; rf < 2; ++rf)
#pragma unroll
      for (int cf = 0; cf < 6; ++cf) {
        acc[rf][cf][0] = 0.f; acc[rf][cf][1] = 0.f;
        acc[rf][cf][2] = 0.f; acc[rf][cf][3] = 0.f;
      }
    const int mfbase = mt * 16 + wid * 2;    // wave owns 32 rows = 2 row-frags
    const unsigned char* ap = Asw + (size_t)mfbase * 24 * 512 + l * 8;

    long a0 = *(const long*)(ap);
    long a1 = *(const long*)(ap + 24 * 512);
    long b[6], a0n, a1n, bn[6];
#pragma unroll
    for (int cf = 0; cf < 6; ++cf)
      b[cf] = *(const long*)(&Bs[cb[cf] ^ xm[cf]]);

#pragma unroll 1
    for (int ks = 0; ks < 24; ks += 2) {     // even/odd 1-deep pipeline
      int k1 = ks + 1;
      a0n = *(const long*)(ap + k1 * 512);
      a1n = *(const long*)(ap + (24 + k1) * 512);
#pragma unroll
      for (int cf = 0; cf < 6; ++cf)
        bn[cf] = *(const long*)(&Bs[(cb[cf] + k1 * 32) ^ xm[cf]]);
#pragma unroll
      for (int cf = 0; cf < 6; ++cf) {
        acc[0][cf] = __builtin_amdgcn_mfma_f32_16x16x32_fp8_fp8(a0, b[cf], acc[0][cf], 0, 0, 0);
        acc[1][cf] = __builtin_amdgcn_mfma_f32_16x16x32_fp8_fp8(a1, b[cf], acc[1][cf], 0, 0, 0);
      }
      int k2 = (ks + 2 < 24) ? ks + 2 : 0;
      a0 = *(const long*)(ap + k2 * 512);
      a1 = *(const long*)(ap + (24 + k2) * 512);
#pragma unroll
      for (int cf = 0; cf < 6; ++cf)
        b[cf] = *(const long*)(&Bs[(cb[cf] + k2 * 32) ^ xm[cf]]);
#pragma unroll
      for (int cf = 0; cf < 6; ++cf) {
        acc[0][cf] = __builtin_amdgcn_mfma_f32_16x16x32_fp8_fp8(a0n, bn[cf], acc[0][cf], 0, 0, 0);
        acc[1][cf] = __builtin_amdgcn_mfma_f32_16x16x32_fp8_fp8(a1n, bn[cf], acc[1][cf], 0, 0, 0);
      }
    }

    // ---- epilogue: min over 96 cols ----
    const int rowbase = mt * 256 + wid * 32;
#pragma unroll
    for (int rf = 0; rf < 2; ++rf) {
#pragma unroll
      for (int reg = 0; reg < 4; ++reg) {
        float v = t2s[lc] - 2.f * acc[rf][0][reg];
#pragma unroll
        for (int cf = 1; cf < 6; ++cf)
          v = fminf(v, t2s[cf * 16 + lc] - 2.f * acc[rf][cf][reg]);
#pragma unroll
        for (int s = 1; s < 16; s <<= 1) v = fminf(v, __shfl_xor(v, s));
        if (lc == 0)
          bmin[(size_t)chunk * NQ + rowbase + rf * 16 + lg * 4 + reg] = v;
      }
    }
  }
}

// ------- Pass B1: per-query global min -------
__global__ __launch_bounds__(256) void passB1(const float* __restrict__ bmin,
                                              unsigned int* __restrict__ gmin) {
  int qg = blockIdx.x >> 4, cs = blockIdx.x & 15;
  int w = threadIdx.x >> 6, l = threadIdx.x & 63;
  int q = qg * 64 + l;
  float m = 3.0e38f;
  for (int j = cs * 4 + w; j < NCHUNK; j += 64)
    m = fminf(m, bmin[(size_t)j * NQ + q]);
  __shared__ float sm[4][64];
  sm[w][l] = m;
  __syncthreads();
  if (threadIdx.x < 64) {
    float v = fminf(fminf(sm[0][l], sm[1][l]), fminf(sm[2][l], sm[3][l]));
    atomicMin(&gmin[q], fenc(v));
  }
}

// ------- Pass B2: emit candidate blocks within min+MARGIN -------
__global__ __launch_bounds__(256) void passB2(const float* __restrict__ bmin,
                                              const unsigned int* __restrict__ gmin,
                                              unsigned int* __restrict__ cnt,
                                              unsigned int* __restrict__ cand) {
  int qg = blockIdx.x >> 4, cs = blockIdx.x & 15;
  int w = threadIdx.x >> 6, l = threadIdx.x & 63;
  int q = qg * 64 + l;
  float thr = fdec(gmin[q]) + MARGIN;
  for (int j = cs * 4 + w; j < NCHUNK; j += 64) {
    if (bmin[(size_t)j * NQ + q] <= thr) {
      unsigned int pos = atomicAdd(cnt, 1u);
      if (pos < MAXC) cand[pos] = ((unsigned int)q << 16) | (unsigned int)j;
    }
  }
}

// ---- Pass C1: fp8 column filter over X8; 4-col ILP, 32 waves/CU ----
// R12 was latency-bound (21% occupancy, serial col chain, 618 GB/s).
__global__ __launch_bounds__(256) void passC1(
    const float* __restrict__ x, const unsigned int* __restrict__ X8,
    const float* __restrict__ T2, const unsigned int* __restrict__ gmin,
    const unsigned int* __restrict__ cnt, const unsigned int* __restrict__ cand,
    unsigned int* __restrict__ cnt2, unsigned int* __restrict__ cand2) {
  unsigned int count = *cnt;
  if (count > MAXC) count = MAXC;
  int w = threadIdx.x >> 6, l = threadIdx.x & 63;
  for (unsigned int t = blockIdx.x * 4 + w; t < count; t += gridDim.x * 4) {
    unsigned int cd = cand[t];
    int q = cd >> 16;
    int blk = cd & 0xFFFF;
    float thr = fdec(gmin[q]) + MARGIN;
    // quantize this lane's 12 query dims (same pk path as stage => identical)
    float xv[12];
    {
      const float* xq = x + (size_t)q * DIM + l * 12;
      f32x4 a = *(const f32x4*)(xq);
      f32x4 b = *(const f32x4*)(xq + 4);
      f32x4 c = *(const f32x4*)(xq + 8);
      unsigned int w0 = pk_lo(a[0], a[1]); w0 = pk_hi(w0, a[2], a[3]);
      unsigned int w1 = pk_lo(b[0], b[1]); w1 = pk_hi(w1, b[2], b[3]);
      unsigned int w2 = pk_lo(c[0], c[1]); w2 = pk_hi(w2, c[2], c[3]);
      UNPK4(&xv[0], w0); UNPK4(&xv[4], w1); UNPK4(&xv[8], w2);
    }
    int n0 = blk * BN;
    int ncap = (n0 + BN <= N_TRAIN) ? BN : (N_TRAIN - n0);
    const unsigned int* xb = X8 + (size_t)n0 * 192 + l * 3;
    for (int col = 0; col < ncap; col += 4) {       // BN%4==0: no tail
      // 4 independent load->dot->reduce chains in flight
      u32x3 tw0 = *(const u32x3*)(xb + (size_t)(col + 0) * 192);
      u32x3 tw1 = *(const u32x3*)(xb + (size_t)(col + 1) * 192);
      u32x3 tw2 = *(const u32x3*)(xb + (size_t)(col + 2) * 192);
      u32x3 tw3 = *(const u32x3*)(xb + (size_t)(col + 3) * 192);
      float s0 = 0.f, s1 = 0.f, s2 = 0.f, s3 = 0.f;
      float tv[12];
      UNPK4(&tv[0], tw0[0]); UNPK4(&tv[4], tw0[1]); UNPK4(&tv[8], tw0[2]);
#pragma unroll
      for (int i = 0; i < 12; ++i) s0 = fmaf(tv[i], xv[i], s0);
      UNPK4(&tv[0], tw1[0]); UNPK4(&tv[4], tw1[1]); UNPK4(&tv[8], tw1[2]);
#pragma unroll
      for (int i = 0; i < 12; ++i) s1 = fmaf(tv[i], xv[i], s1);
      UNPK4(&tv[0], tw2[0]); UNPK4(&tv[4], tw2[1]); UNPK4(&tv[8], tw2[2]);
#pragma unroll
      for (int i = 0; i < 12; ++i) s2 = fmaf(tv[i], xv[i], s2);
      UNPK4(&tv[0], tw3[0]); UNPK4(&tv[4], tw3[1]); UNPK4(&tv[8], tw3[2]);
#pragma unroll
      for (int i = 0; i < 12; ++i) s3 = fmaf(tv[i], xv[i], s3);
#pragma unroll
      for (int sh = 1; sh < 64; sh <<= 1) {
        s0 += __shfl_xor(s0, sh); s1 += __shfl_xor(s1, sh);
        s2 += __shfl_xor(s2, sh); s3 += __shfl_xor(s3, sh);
      }
      if (l == 0) {
        float v0 = T2[n0 + col] - 2.f * s0;
        float v1 = T2[n0 + col + 1] - 2.f * s1;
        float v2 = T2[n0 + col + 2] - 2.f * s2;
        float v3 = T2[n0 + col + 3] - 2.f * s3;
        if (v0 <= thr) { unsigned p = atomicAdd(cnt2, 1u); if (p < MAXC) cand2[p] = ((unsigned)q << 17) | (unsigned)(n0 + col); }
        if (v1 <= thr) { unsigned p = atomicAdd(cnt2, 1u); if (p < MAXC) cand2[p] = ((unsigned)q << 17) | (unsigned)(n0 + col + 1); }
        if (v2 <= thr) { unsigned p = atomicAdd(cnt2, 1u); if (p < MAXC) cand2[p] = ((unsigned)q << 17) | (unsigned)(n0 + col + 2); }
        if (v3 <= thr) { unsigned p = atomicAdd(cnt2, 1u); if (p < MAXC) cand2[p] = ((unsigned)q << 17) | (unsigned)(n0 + col + 3); }
      }
    }
  }
}

// ---- Pass C2: exact fp32 on surviving columns ----
__global__ __launch_bounds__(256) void passC2(
    const float* __restrict__ x, const float* __restrict__ Xt,
    const unsigned int* __restrict__ cnt2, const unsigned int* __restrict__ cand2,
    unsigned long long* __restrict__ res) {
  unsigned int count = *cnt2;
  if (count > MAXC) count = MAXC;
  int w = threadIdx.x >> 6, l = threadIdx.x & 63;
  for (unsigned int t = blockIdx.x * 4 + w; t < count; t += gridDim.x * 4) {
    unsigned int cd = cand2[t];
    int q = cd >> 17;
    int n = cd & 0x1FFFF;
    const float* xq = x + (size_t)q * DIM;
    const float* tn = Xt + (size_t)n * DIM;
    float s = 0.f;
#pragma unroll
    for (int i = 0; i < 12; ++i) {
      float d = xq[i * 64 + l] - tn[i * 64 + l];
      s = fmaf(d, d, s);
    }
#pragma unroll
    for (int sh = 1; sh < 64; sh <<= 1) s += __shfl_xor(s, sh);
    if (l == 0) {
      unsigned long long key =
          ((unsigned long long)__builtin_bit_cast(unsigned int, s) << 32) | (unsigned int)n;
      atomicMin(res + q, key);                // min d2, tie -> lowest index
    }
  }
}

// ---- fallback direct exact pass if ws too small for X8 ----
__global__ __launch_bounds__(256) void passC_direct(
    const float* __restrict__ x, const float* __restrict__ Xt,
    const unsigned int* __restrict__ cnt, const unsigned int* __restrict__ cand,
    unsigned long long* __restrict__ res) {
  unsigned int count = *cnt;
  if (count > MAXC) count = MAXC;
  int w = threadIdx.x >> 6, l = threadIdx.x & 63;
  for (unsigned int t = blockIdx.x * 4 + w; t < count; t += gridDim.x * 4) {
    unsigned int cd = cand[t];
    int q = cd >> 16;
    int blk = cd & 0xFFFF;
    const float* xq = x + (size_t)q * DIM;
    float xr[12];
#pragma unroll
    for (int i = 0; i < 12; ++i) xr[i] = xq[i * 64 + l];
    unsigned long long best = ~0ull;
    int n0 = blk * BN;
    int ncap = (n0 + BN <= N_TRAIN) ? BN : (N_TRAIN - n0);
    for (int col = 0; col < ncap; ++col) {
      const float* tn = Xt + (size_t)(n0 + col) * DIM;
      float s = 0.f;
#pragma unroll
      for (int i = 0; i < 12; ++i) {
        float d = xr[i] - tn[i * 64 + l];
        s = fmaf(d, d, s);
      }
#pragma unroll
      for (int sh = 1; sh < 64; sh <<= 1) s += __shfl_xor(s, sh);
      if (l == 0) {
        unsigned long long key =
            ((unsigned long long)__builtin_bit_cast(unsigned int, s) << 32) | (unsigned int)(n0 + col);
        best = (key < best) ? key : best;
      }
    }
    if (l == 0) atomicMin(res + q, best);
  }
}

// ---------------- Pass D: gather ----------------
__global__ void passD(const unsigned long long* __restrict__ res,
                      const float* __restrict__ Y, float* __restrict__ out) {
  int t = blockIdx.x * 256 + threadIdx.x;
  if (t < NQ * 24) {
    int q = t / 24, j = t - q * 24;
    unsigned int idx = (unsigned int)(res[q] & 0xFFFFFFFFu);
    out[t] = Y[(size_t)idx * 24 + j];
  }
}

extern "C" void kernel_launch(void* const* d_in, const int* in_sizes, int n_in,
                              void* d_out, int out_size, void* d_ws, size_t ws_size,
                              hipStream_t stream) {
  const float* x  = (const float*)d_in[0];   // [1024][768]
  const float* Xt = (const float*)d_in[1];   // [100000][768]
  const float* Y  = (const float*)d_in[2];   // [100000][24]
  float* out = (float*)d_out;                // [1024*24]
  char* ws = (char*)d_ws;
  unsigned long long* res  = (unsigned long long*)(ws);        // 8192 B
  unsigned int*       cnt  = (unsigned int*)(ws + 8192);       // cnt[0], cnt2=cnt[1]
  unsigned int*       gmin = (unsigned int*)(ws + 8448);       // 4096 B
  unsigned int*       cand = (unsigned int*)(ws + 12544);      // 256 KB
  unsigned int*       cand2= (unsigned int*)(ws + 274688);     // 256 KB
  unsigned char*      Asw  = (unsigned char*)(ws + 536832);    // 768 KB
  float*              T2   = (float*)(ws + 1323264);           // 400 KB
  float*              bmin = (float*)(ws + 1723392);           // 4.27 MB
  unsigned int*       X8   = (unsigned int*)(ws + 5991424);    // 76.8 MB

  int useX8 = (ws_size >= 82791424ull) ? 1 : 0;

  hipLaunchKernelGGL(initK,  dim3(1),      dim3(1024), 0, stream, res, gmin, cnt);
  hipLaunchKernelGGL(convA,  dim3(384),    dim3(256),  0, stream, x, Asw);
  hipLaunchKernelGGL(passA,  dim3(NCHUNK), dim3(512),  0, stream, Xt, Asw, bmin, X8, T2, useX8);
  hipLaunchKernelGGL(passB1, dim3(256),    dim3(256),  0, stream, bmin, gmin);
  hipLaunchKernelGGL(passB2, dim3(256),    dim3(256),  0, stream, bmin, gmin, cnt, cand);
  if (useX8) {
    hipLaunchKernelGGL(passC1, dim3(2048), dim3(256),  0, stream,
                       x, X8, T2, gmin, cnt, cand, cnt + 1, cand2);
    hipLaunchKernelGGL(passC2, dim3(512),  dim3(256),  0, stream,
                       x, Xt, cnt + 1, cand2, res);
  } else {
    hipLaunchKernelGGL(passC_direct, dim3(2048), dim3(256), 0, stream,
                       x, Xt, cnt, cand, res);
  }
  hipLaunchKernelGGL(passD,  dim3(96),     dim3(256),  0, stream, res, Y, out);
}